// Round 7
// baseline (87.006 us; speedup 1.0000x reference)
//
#include <hip/hip_runtime.h>

#define N 1024
#define D 128
#define PAD 132   // 128+4: rows 16B-aligned (528 B), bank stride 4 -> 2-way (free)
#define MAGIC 0x3C96A5E1u  // poison-proof flag value (proven != poison in R2)

// ---------------------------------------------------------------------------
// Single-kernel fused scores+relu+exp+rowsum+normalize.
// Compute core = R4's proven best (64x32 tile, 512 thr = 2 d-groups x 256,
// micro 4x2, W in LDS, 512 blocks -> 2/CU).
//
// ROUND-7 CHANGE: kill the scale kernel. Cross-block rowsum via a per-stripe
// write-once flag protocol (NOT R2's single global counter, which serialized
// 512 RMWs on one line for ~30 us):
//   - block (bx, stripe=by) stores its 64 row-partials to part[row][bx]
//     (agent-scope relaxed stores), __syncthreads (drains vmcnt),
//     threadfence, then sets flags[stripe*32+bx] = MAGIC (own word, no RMW,
//     no contention, no init: the per-iteration 256 MiB ws poison resets it).
//   - poll: wave 0 lanes 0..31 read the stripe's 32 flags (read-only lines).
//   - then re-reduce 64x32 partials (agent loads, LLC-hot), scale the
//     in-register exp values, write E exactly once.
// Saves: scale launch edge + scale body + 8 MB of E re-read/re-write.
// Co-residency: 512 blocks, LDS 51.4 KB -> 3 blocks/CU cap >= 2 needed.
// Spins iteration-capped: protocol failure = wrong answer, not a hang.
// ---------------------------------------------------------------------------
__global__ __launch_bounds__(512, 4) void fused_kernel(
    const float* __restrict__ x, const float* __restrict__ w,
    const float* __restrict__ bias, float* __restrict__ E,
    unsigned int* __restrict__ ws) {
  __shared__ float sxi[64 * PAD];   // 33.8 KB; combine buffer aliases this
  __shared__ float sxj[32 * PAD];   // 16.9 KB
  __shared__ float sw[D];           // 512 B
  __shared__ float srow[64];

  unsigned int* flags = ws;                              // [512] stride 4 words
  float* part = reinterpret_cast<float*>(ws) + 4096;     // [1024][32] f32

  const int t  = threadIdx.x;
  const int bi = blockIdx.y * 64;
  const int bj = blockIdx.x * 32;

  // ---- stage tiles + w: coalesced float4, one barrier ----------------------
  {
    const int c  = t & 31;
    const int r0 = t >> 5;   // 0..15
    #pragma unroll
    for (int p = 0; p < 4; ++p) {   // 64 rows of xi
      const int r = r0 + p * 16;
      const float4 v = reinterpret_cast<const float4*>(x)[(bi + r) * 32 + c];
      *reinterpret_cast<float4*>(&sxi[r * PAD + c * 4]) = v;
    }
    #pragma unroll
    for (int p = 0; p < 2; ++p) {   // 32 rows of xj
      const int r = r0 + p * 16;
      const float4 v = reinterpret_cast<const float4*>(x)[(bj + r) * 32 + c];
      *reinterpret_cast<float4*>(&sxj[r * PAD + c * 4]) = v;
    }
    if (t < 32)
      *reinterpret_cast<float4*>(&sw[t * 4]) =
          reinterpret_cast<const float4*>(w)[t];
  }
  __syncthreads();

  // d-group: wave-uniform (waves 0-3 -> g=0, waves 4-7 -> g=1)
  const int g  = __builtin_amdgcn_readfirstlane(t >> 8);   // 0..1
  const int s  = t & 255;
  const int tx = s & 15;   // cols tx + 16*b, b=0..1
  const int ty = s >> 4;   // rows ty + 16*a, a=0..3
  const int d0 = g * 64;

  float acc[4][2];
  #pragma unroll
  for (int a = 0; a < 4; ++a)
    #pragma unroll
    for (int b = 0; b < 2; ++b) acc[a][b] = 0.f;

  #pragma unroll 4
  for (int dc = 0; dc < 16; ++dc) {   // 16 chunks of 4 d-values (64 per group)
    const int d = d0 + dc * 4;
    const float4 W = *reinterpret_cast<const float4*>(&sw[d]);  // LDS broadcast
    float4 A[4], B[2];
    #pragma unroll
    for (int a = 0; a < 4; ++a)
      A[a] = *reinterpret_cast<const float4*>(&sxi[(ty + 16 * a) * PAD + d]);
    #pragma unroll
    for (int b = 0; b < 2; ++b)
      B[b] = *reinterpret_cast<const float4*>(&sxj[(tx + 16 * b) * PAD + d]);

    #pragma unroll
    for (int a = 0; a < 4; ++a) {
      #pragma unroll
      for (int b = 0; b < 2; ++b) {
        float v = acc[a][b];
        v = fmaf(fabsf(A[a].x - B[b].x), W.x, v);
        v = fmaf(fabsf(A[a].y - B[b].y), W.y, v);
        v = fmaf(fabsf(A[a].z - B[b].z), W.z, v);
        v = fmaf(fabsf(A[a].w - B[b].w), W.w, v);
        acc[a][b] = v;
      }
    }
  }
  __syncthreads();   // tiles dead; sxi becomes the combine buffer

  // ---- combine the 2 d-partials: g1 writes, g0 sums ------------------------
  float* comb = sxi;   // [256][9]: odd stride -> 2-way alias (free)
  if (g == 1) {
    float* dst = comb + s * 9;
    #pragma unroll
    for (int k = 0; k < 8; ++k) dst[k] = acc[k >> 1][k & 1];
  }
  __syncthreads();

  if (g == 0) {
    const float* src = comb + s * 9;
    #pragma unroll
    for (int k = 0; k < 8; ++k) acc[k >> 1][k & 1] += src[k];

    // ---- bias + relu + exp (no max-sub: proven numerics R2-R6) ------------
    const float bv = bias[0];
    #pragma unroll
    for (int a = 0; a < 4; ++a) {
      float p = 0.f;
      #pragma unroll
      for (int b = 0; b < 2; ++b) {
        const float ev = __expf(fmaxf(acc[a][b] + bv, 0.f));
        acc[a][b] = ev;   // acc now holds exp values (stay in VGPRs)
        p += ev;
      }
      #pragma unroll
      for (int o = 1; o < 16; o <<= 1) p += __shfl_xor(p, o, 64);
      if (tx == 0)
        __hip_atomic_store(&part[(bi + ty + 16 * a) * 32 + blockIdx.x], p,
                           __ATOMIC_RELAXED, __HIP_MEMORY_SCOPE_AGENT);
    }
  }
  __syncthreads();   // drains vmcnt: all 64 partial stores of this block done

  // ---- announce: own flag word, write-once, no contention ------------------
  if (t == 0) {
    __threadfence();
    __hip_atomic_store(&flags[(blockIdx.y * 32 + blockIdx.x) * 4], MAGIC,
                       __ATOMIC_RELEASE, __HIP_MEMORY_SCOPE_AGENT);
  }

  // ---- poll the stripe's 32 flags (wave 0, read-only lines) ----------------
  if (t < 64) {
    bool ok = (t >= 32);
    const unsigned fidx = (blockIdx.y * 32u + (unsigned)t) * 4u;
    for (unsigned it = 0; it < (1u << 20); ++it) {
      if (!ok)
        ok = (__hip_atomic_load(&flags[fidx], __ATOMIC_ACQUIRE,
                                __HIP_MEMORY_SCOPE_AGENT) == MAGIC);
      if (__ballot(ok) == ~0ull) break;
      __builtin_amdgcn_s_sleep(1);
    }
  }
  __syncthreads();   // all waves held until wave 0 exits the poll

  // ---- cooperative rowsum: 64 rows x 32 partials, 4 loads/thread -----------
  {
    const int r = t >> 3;          // 0..63
    const int q = t & 7;           // 8 threads/row, 4 slots each
    float sum = 0.f;
    #pragma unroll
    for (int k = 0; k < 4; ++k)
      sum += __hip_atomic_load(&part[(bi + r) * 32 + q * 4 + k],
                               __ATOMIC_RELAXED, __HIP_MEMORY_SCOPE_AGENT);
    sum += __shfl_xor(sum, 1, 64);
    sum += __shfl_xor(sum, 2, 64);
    sum += __shfl_xor(sum, 4, 64);
    if (q == 0) srow[r] = sum;
  }
  __syncthreads();

  // ---- normalize from registers, single write of E -------------------------
  if (g == 0) {
    #pragma unroll
    for (int a = 0; a < 4; ++a) {
      const int row = bi + ty + 16 * a;
      const float rs = 1.0f / srow[ty + 16 * a];
      #pragma unroll
      for (int b = 0; b < 2; ++b)
        E[row * N + bj + tx + 16 * b] = acc[a][b] * rs;
    }
  }
}

extern "C" void kernel_launch(void* const* d_in, const int* in_sizes, int n_in,
                              void* d_out, int out_size, void* d_ws, size_t ws_size,
                              hipStream_t stream) {
  const float* x = (const float*)d_in[0];
  const float* w = (const float*)d_in[1];
  const float* b = (const float*)d_in[2];
  float* out = (float*)d_out;
  unsigned int* ws = (unsigned int*)d_ws;

  dim3 grid(N / 32, N / 64);   // (32,16) = 512 blocks, 2/CU, all co-resident
  fused_kernel<<<grid, 512, 0, stream>>>(x, w, b, out, ws);
}

// Round 8
// 71.048 us; speedup vs baseline: 1.2246x; 1.2246x over previous
//
#include <hip/hip_runtime.h>

#define N 1024
#define D 128
#define PAD 132   // 128+4: rows 16B-aligned (528 B), bank stride 4 -> 2-way (free)

// ---------------------------------------------------------------------------
// ROUND-8: exploit symmetry. S[i][j] = S[j][i] (|x_i-x_j| symmetric, shared w)
// -> compute only the upper stripe-triangle: 540K pairs vs 1049K (0.52x).
//
// Tiling: 32x32 stripe tiles (p<=q), each split into two 16-row halves:
//   block b: tile t=b>>1, h=b&1; (p,q) from triangular enumeration of t.
//   rows bi = 32p+16h (16 rows of stripe p), cols bj = 32q (32 cols).
//   Grid = 2*528 = 1056 blocks (4.125/CU -> 1.21x tail), 128 threads each.
//
// Off-diag (p<q): write direct tile E[bi..][bj..] AND transpose tile
//   E[bj..][bi..] (via 2KB LDS transpose -> coalesced float4 stores).
//   Partials: partA[row][q] for direct rows (unique writer: h splits rows);
//   partB[row][2p+h] for transpose rows (unique writer: h splits cols).
// Diag (p==q): full 16x32 computed (cells appear once globally), direct-only.
//
// Row r (stripe s=r>>5) written slots: partA[r][q] for q>=s; partB[r][l] for
// l<2s. Scale kernel masks exactly those -> poisoned ws needs no init, and
// there are no atomics and no cross-block sync (R2/R7 lesson).
// ---------------------------------------------------------------------------
__global__ __launch_bounds__(128, 2) void scores_kernel(
    const float* __restrict__ x, const float* __restrict__ w,
    const float* __restrict__ bias, float* __restrict__ E,
    float* __restrict__ partA, float* __restrict__ partB) {
  __shared__ float sxi[16 * PAD];    // 8.4 KB
  __shared__ float sxj[32 * PAD];    // 16.9 KB
  __shared__ float sw[D];            // 512 B
  __shared__ float ldst[16 * 33];    // 2.1 KB transpose buffer

  const int t = threadIdx.x;

  // ---- triangular enumeration (wave-uniform scalar math) -------------------
  const int tt = blockIdx.x >> 1;    // tile index 0..527
  const int h  = blockIdx.x & 1;     // row-half
  int q = (int)((sqrtf(8.0f * (float)tt + 1.0f) - 1.0f) * 0.5f);
  while ((q + 1) * (q + 2) / 2 <= tt) ++q;   // fixup for sqrt rounding
  while (q * (q + 1) / 2 > tt) --q;
  const int p  = tt - q * (q + 1) / 2;       // p <= q
  const int bi = p * 32 + h * 16;    // 16 rows
  const int bj = q * 32;             // 32 cols

  // ---- stage xi(16 rows) + xj(32 rows) + w: coalesced float4 ---------------
  {
    const int c  = t & 31;   // float4 column
    const int r0 = t >> 5;   // 0..3
    #pragma unroll
    for (int k = 0; k < 4; ++k) {    // 16 rows of xi
      const int r = r0 + k * 4;
      *reinterpret_cast<float4*>(&sxi[r * PAD + c * 4]) =
          reinterpret_cast<const float4*>(x)[(bi + r) * 32 + c];
    }
    #pragma unroll
    for (int k = 0; k < 8; ++k) {    // 32 rows of xj
      const int r = r0 + k * 4;
      *reinterpret_cast<float4*>(&sxj[r * PAD + c * 4]) =
          reinterpret_cast<const float4*>(x)[(bj + r) * 32 + c];
    }
    if (t < 32)
      *reinterpret_cast<float4*>(&sw[t * 4]) =
          reinterpret_cast<const float4*>(w)[t];
  }
  __syncthreads();

  const int tx = t & 15;   // j = tx + 16*b, b=0..1
  const int ty = t >> 4;   // i = ty + 8*a,  a=0..1 (0..7 over 2 waves)

  float acc[2][2];
  acc[0][0] = acc[0][1] = acc[1][0] = acc[1][1] = 0.f;

  #pragma unroll 4
  for (int dc = 0; dc < 32; ++dc) {   // 32 chunks of 4 d-values
    const int d = dc * 4;
    const float4 W = *reinterpret_cast<const float4*>(&sw[d]);  // broadcast
    float4 A[2], B[2];
    #pragma unroll
    for (int a = 0; a < 2; ++a)   // 4 addrs/wave, 16-lane broadcast
      A[a] = *reinterpret_cast<const float4*>(&sxi[(ty + 8 * a) * PAD + d]);
    #pragma unroll
    for (int b = 0; b < 2; ++b)   // 16 addrs/wave, 2-way alias (free)
      B[b] = *reinterpret_cast<const float4*>(&sxj[(tx + 16 * b) * PAD + d]);

    #pragma unroll
    for (int a = 0; a < 2; ++a) {
      #pragma unroll
      for (int b = 0; b < 2; ++b) {
        float v = acc[a][b];
        v = fmaf(fabsf(A[a].x - B[b].x), W.x, v);
        v = fmaf(fabsf(A[a].y - B[b].y), W.y, v);
        v = fmaf(fabsf(A[a].z - B[b].z), W.z, v);
        v = fmaf(fabsf(A[a].w - B[b].w), W.w, v);
        acc[a][b] = v;
      }
    }
  }

  // ---- epilogue: bias + relu + exp (no max-sub: proven numerics R2-R7) -----
  const float bv = bias[0];
  float e[2][2];
  #pragma unroll
  for (int a = 0; a < 2; ++a) {
    float pd = 0.f;
    #pragma unroll
    for (int b = 0; b < 2; ++b) {
      const float ev = __expf(fmaxf(acc[a][b] + bv, 0.f));
      e[a][b] = ev;
      pd += ev;
    }
    // direct row partial: reduce over the 16-lane tx group
    #pragma unroll
    for (int o = 1; o < 16; o <<= 1) pd += __shfl_xor(pd, o, 64);
    if (tx == 0) partA[(bi + ty + 8 * a) * 32 + q] = pd;
  }

  // ---- direct tile write ---------------------------------------------------
  #pragma unroll
  for (int a = 0; a < 2; ++a) {
    const int row = bi + ty + 8 * a;
    #pragma unroll
    for (int b = 0; b < 2; ++b)
      E[row * N + bj + tx + 16 * b] = e[a][b];
  }

  // ---- transpose tile + partB (off-diagonal blocks only) -------------------
  if (p != q) {
    #pragma unroll
    for (int a = 0; a < 2; ++a)
      #pragma unroll
      for (int b = 0; b < 2; ++b)
        ldst[(ty + 8 * a) * 33 + tx + 16 * b] = e[a][b];
    __syncthreads();

    // read transposed: thread -> out-row rj (=orig col), 4 consecutive cols
    const int rj = t >> 2;          // 0..31
    const int c0 = (t & 3) * 4;     // 0,4,8,12
    float v0 = ldst[(c0 + 0) * 33 + rj];
    float v1 = ldst[(c0 + 1) * 33 + rj];
    float v2 = ldst[(c0 + 2) * 33 + rj];
    float v3 = ldst[(c0 + 3) * 33 + rj];
    // coalesced float4 store of the transpose tile (bi+c0 is 16B-aligned)
    *reinterpret_cast<float4*>(&E[(bj + rj) * N + bi + c0]) =
        make_float4(v0, v1, v2, v3);
    // transpose row partial: sum over the 16 i-cols (4 lanes share rj)
    float ps = (v0 + v1) + (v2 + v3);
    ps += __shfl_xor(ps, 1, 64);
    ps += __shfl_xor(ps, 2, 64);
    if ((t & 3) == 0) partB[(bj + rj) * 64 + 2 * p + h] = ps;
  }
}

// ---------------------------------------------------------------------------
// Phase B: scale. One block per row. Row r (stripe s): valid partials are
// partA[r][l] for l>=s and partB[r][l] for l<2s; everything else is poison
// and masked out. All 4 waves compute the reduce redundantly.
// ---------------------------------------------------------------------------
__global__ __launch_bounds__(256) void scale_kernel(
    float* __restrict__ S, const float* __restrict__ partA,
    const float* __restrict__ partB) {
  const int row = blockIdx.x;
  const int s   = row >> 5;
  const int t   = threadIdx.x;
  const int l   = t & 63;

  float v = 0.f;
  if (l < 32 && l >= s) v += partA[row * 32 + l];
  if (l < 2 * s)        v += partB[row * 64 + l];
  #pragma unroll
  for (int o = 1; o < 64; o <<= 1) v += __shfl_xor(v, o, 64);
  const float r = 1.0f / v;

  float4* rowp = reinterpret_cast<float4*>(S + row * N);
  float4 u = rowp[t];
  u.x *= r; u.y *= r; u.z *= r; u.w *= r;
  rowp[t] = u;
}

extern "C" void kernel_launch(void* const* d_in, const int* in_sizes, int n_in,
                              void* d_out, int out_size, void* d_ws, size_t ws_size,
                              hipStream_t stream) {
  const float* x = (const float*)d_in[0];
  const float* w = (const float*)d_in[1];
  const float* b = (const float*)d_in[2];
  float* out = (float*)d_out;
  float* partA = (float*)d_ws;              // [1024][32] f32, 128 KB
  float* partB = partA + 1024 * 32;         // [1024][64] f32, 256 KB

  scores_kernel<<<1056, 128, 0, stream>>>(x, w, b, out, partA, partB);
  scale_kernel<<<N, 256, 0, stream>>>(out, partA, partB);
}